// Round 9
// baseline (3117.630 us; speedup 1.0000x reference)
//
#include <hip/hip_runtime.h>
#include <hip/hip_bf16.h>
#include <stdint.h>

typedef unsigned short u16;
typedef unsigned int u32;
typedef unsigned long long u64;
typedef float f32x4 __attribute__((ext_vector_type(4)));
typedef short bf16x8 __attribute__((ext_vector_type(8)));
typedef unsigned u32x4 __attribute__((ext_vector_type(4)));   // native vector for asm 'v'

#define NB 32
#define NL 1024
#define ND 512
#define NH 512
#define G4 2048
#define NOUT 100
#define NFF 256
#define HSTR 528   // LDS row stride (halfwords): 264 dwords == 8 mod 32 -> uniform 2-way (free) a-frag reads
#define SPIN_CAP (1 << 15)   // ~8 ms worst case per spin: degrade to fast-fail, never timeout

__device__ inline u16 f2b(float f) {
    union { float f; unsigned i; } c; c.f = f;
    unsigned i = c.i;
    return (u16)((i + 0x7FFFu + ((i >> 16) & 1u)) >> 16);
}
__device__ inline bf16x8 cvt8(const float* __restrict__ p) {
    float4 a = *(const float4*)p;
    float4 b = *(const float4*)(p + 4);
    bf16x8 r;
    u16* h = (u16*)&r;
    h[0] = f2b(a.x); h[1] = f2b(a.y); h[2] = f2b(a.z); h[3] = f2b(a.w);
    h[4] = f2b(b.x); h[5] = f2b(b.y); h[6] = f2b(b.z); h[7] = f2b(b.w);
    return r;
}
__device__ inline f32x4 MF(bf16x8 a, bf16x8 b, f32x4 c) {
    return __builtin_amdgcn_mfma_f32_16x16x32_bf16(a, b, c, 0, 0, 0);
}
__device__ inline float tanh_f(float x) {
    float xx = fminf(fmaxf(x, -15.f), 15.f);
    float e = __expf(2.f * xx);
    return (e - 1.f) / (e + 1.f);
}
__device__ inline float sigm_f(float x) { return 1.f / (1.f + __expf(-x)); }

// 16-B SYSTEM-coherent load/store (sc0 sc1: scope >= agent, to the coherence point).
// One dwordx4 = one LLC request -> tag+payload move atomically within the aligned 16 B.
__device__ inline u32x4 ld_sc16(const u32x4* p) {
    u32x4 r;
    asm volatile("global_load_dwordx4 %0, %1, off sc0 sc1\n\t"
                 "s_waitcnt vmcnt(0)"
                 : "=&v"(r) : "v"(p) : "memory");
    return r;
}
__device__ inline void ld2_issue(const u32x4* p1, const u32x4* p2, u32x4& r1, u32x4& r2) {
    asm volatile("global_load_dwordx4 %0, %2, off sc0 sc1\n\t"
                 "global_load_dwordx4 %1, %3, off sc0 sc1"
                 : "=&v"(r1), "=&v"(r2) : "v"(p1), "v"(p2) : "memory");
}
__device__ inline void wait_vm2(u32x4& r1, u32x4& r2) {
    asm volatile("s_waitcnt vmcnt(0)" : "+v"(r1), "+v"(r2) :: "memory");
}
__device__ inline void st_sc16(u32x4* p, u32x4 v) {
    asm volatile("global_store_dwordx4 %0, %1, off sc0 sc1"
                 :: "v"(p), "v"(v) : "memory");
}

// f32 -> bf16 pre-cast (weights for k_attn): one quad per thread.
__global__ __launch_bounds__(256) void k_wcast(const float* __restrict__ s,
                                               u16* __restrict__ d, int n4) {
    int i = blockIdx.x * 256 + threadIdx.x;
    if (i >= n4) return;
    float4 v = *(const float4*)&s[(size_t)i * 4];
    u64 pk = (u64)f2b(v.x) | ((u64)f2b(v.y) << 16) |
             ((u64)f2b(v.z) << 32) | ((u64)f2b(v.w) << 48);
    *(u64*)&d[(size_t)i * 4] = pk;
}

// cbias[b][r] = emb[concepts[b]] . Wih[r, 512:1024] + bih[r] + bhh[r]   (all fp32)
__global__ __launch_bounds__(256) void k_cbias(const float* __restrict__ emb,
                                               const int* __restrict__ concepts,
                                               const float* __restrict__ Wih,
                                               const float* __restrict__ bih,
                                               const float* __restrict__ bhh,
                                               float* __restrict__ cbias) {
    __shared__ float e[ND];
    int b = blockIdx.x;
    int r = blockIdx.y * 256 + threadIdx.x;
    int c = concepts[b];
    for (int i = threadIdx.x; i < ND; i += 256) e[i] = emb[c * ND + i];
    __syncthreads();
    const float* wrow = Wih + (size_t)r * 1024 + 512;
    float acc = 0.f;
#pragma unroll 4
    for (int k4 = 0; k4 < 128; k4++) {
        float4 wv = *(const float4*)&wrow[k4 * 4];
        acc += e[k4 * 4 + 0] * wv.x + e[k4 * 4 + 1] * wv.y +
               e[k4 * 4 + 2] * wv.z + e[k4 * 4 + 3] * wv.w;
    }
    cbias[b * G4 + r] = acc + bih[r] + bhh[r];
}

// Persistent LSTM, batch-split: 8 groups x 32 blocks; group g owns batch rows [4g,4g+4),
// block k owns h lanes [16k,16k+16).
// v10 = v9 (barrier-drain-free loop order) with SPIN_CAP shrunk 2^22 -> 2^15 so any
// exchange pathology fast-fails the bench instead of timing out the container.
//  - Loop order: spin-issue -> x-MFMA -> x-commit -> spin-wait+hsb -> barrier C (drains
//    only LDS writes; NO fresh vmem outstanding) -> prefetch-issue -> h-MFMA -> cell ->
//    publish. The x[t+2] prefetch issued post-C is consumed at t+1's commit (~800 cy) and
//    fully drained only at t+1's spin wait -> HBM latency covered; barrier C's implicit
//    `s_waitcnt vmcnt(0)` no longer exposes prefetch latency (v8's hidden stall).
//  - All v8-validated structure kept: wave-local cell via gate-interleaved B cols (no
//    gbuf/barrier B), tagged 16-B exchange units, weights in regs, HSTR=528.
__global__ __launch_bounds__(256, 1) void k_lstm(const float* __restrict__ x,
                                                 const float* __restrict__ Wih,
                                                 const float* __restrict__ Whh,
                                                 const float* __restrict__ cbias,
                                                 u16* __restrict__ out,
                                                 u32x4* __restrict__ hx) {
    __shared__ __align__(16) u16 hsb[4 * HSTR];         // h[t-1] tile, bf16
    __shared__ __align__(16) u16 xb[2][4 * HSTR];       // x double buffer, bf16
    int g = blockIdx.x & 7, k = blockIdx.x >> 3;
    int tid = threadIdx.x;
    int w = tid >> 6, l = tid & 63, quad = l >> 4, lane = l & 15;
    int jj = k * 16;
    int b0 = g * 4;
    int rr = w, f0 = l * 8;
    int gidx = l & 3;          // gate index of this lane's C column
    int cidx = lane >> 2;      // h-col offset (0..3) within the wave's 4 columns

    // ---- init: weights -> registers (gate-interleaved B cols), cbias regs, x[0] -> LDS
    bf16x8 bwx[16], bwh[16];
    float cbv0, cbv1, cbv2, cbv3;
    {
        int n = lane;                       // B col
        int wrow = (n & 3) * 512 + jj + w * 4 + (n >> 2);   // weight row for col n
        int q4 = l >> 4;
        const float* wsrc = Wih + (size_t)wrow * 1024 + q4 * 8;  // x-part
        const float* hsrc = Whh + (size_t)wrow * 512 + q4 * 8;
#pragma unroll
        for (int kk = 0; kk < 16; kk++) {
            bwx[kk] = cvt8(wsrc + kk * 32);
            bwh[kk] = cvt8(hsrc + kk * 32);
        }
        // cell constants for (row=gidx, col=jj+w*4+cidx), one per gate
        size_t cb = (size_t)(b0 + gidx) * G4 + jj + w * 4 + cidx;
        cbv0 = cbias[cb + 0 * 512];
        cbv1 = cbias[cb + 1 * 512];
        cbv2 = cbias[cb + 2 * 512];
        cbv3 = cbias[cb + 3 * 512];
        *(bf16x8*)&xb[0][rr * HSTR + f0] = cvt8(&x[((size_t)(b0 + rr) * NL) * ND + f0]);
    }

    // ---- consumer precompute: 512 units (32 blocks x 4 rows x 4 waves), exactly 2/thread
    // unit u = p*16 + r*4 + wv: payload = h[row r][p*16 + wv*4 .. +3]
    u32x4* hxg = hx + (size_t)g * 1024;              // per-group: 2 parity x 512 units
    int p1 = tid >> 4, r1 = (tid >> 2) & 3, w1 = tid & 3;
    int lo1 = r1 * HSTR + p1 * 16 + w1 * 4;          // hsb halfword offset (unit 1)
    int lo2 = lo1 + 256;                             // unit 2: p += 16
    const u32x4* a1base = hxg + tid;
    const u32x4* a2base = hxg + 256 + tid;
    u32x4* myst = hxg + k * 16 + w;                  // + r*4 chosen by builder lane

    // preload x[1] into prefetch regs (committed during iter 0)
    float4 pa, pb;
    {
        const float* px = &x[((size_t)(b0 + rr) * NL + 1) * ND + f0];
        pa = *(const float4*)px; pb = *(const float4*)(px + 4);
    }
    __syncthreads();

    float c_reg = 0.f;   // cell state for (row gidx, col jj+w*4+cidx); dup across quads

    for (int t = 0; t < NL; t++) {
        // ---- issue spin loads FIRST (max hiding under x-MFMA + commit)
        u32x4 A1 = {}, A2 = {};
        const u32x4* A1p = a1base;
        const u32x4* A2p = a2base;
        if (t > 0) {
            int poff = ((t - 1) & 1) * 512;
            A1p = a1base + poff;
            A2p = a2base + poff;
            ld2_issue(A1p, A2p, A1, A2);
        }
        // ---- x-part MFMA, 4 independent accumulator chains (LDS/lgkm only)
        f32x4 ac0 = {}, ac1 = {}, ac2 = {}, ac3 = {};
#pragma unroll
        for (int kk = 0; kk < 16; kk += 4) {
            const u16* xbp = &xb[t & 1][(lane & 3) * HSTR + quad * 8];
            ac0 = MF(*(bf16x8*)&xbp[(kk + 0) * 32], bwx[kk + 0], ac0);
            ac1 = MF(*(bf16x8*)&xbp[(kk + 1) * 32], bwx[kk + 1], ac1);
            ac2 = MF(*(bf16x8*)&xbp[(kk + 2) * 32], bwx[kk + 2], ac2);
            ac3 = MF(*(bf16x8*)&xbp[(kk + 3) * 32], bwx[kk + 3], ac3);
        }
        // ---- commit x[t+1] (prefetch issued at t-1 post-C, ~800 cy ago; the register
        //      use here waits vmcnt(2): retires the prefetch, keeps spin loads in flight)
        if (t + 1 < NL) {
            bf16x8 xv; u16* hh = (u16*)&xv;
            hh[0] = f2b(pa.x); hh[1] = f2b(pa.y); hh[2] = f2b(pa.z); hh[3] = f2b(pa.w);
            hh[4] = f2b(pb.x); hh[5] = f2b(pb.y); hh[6] = f2b(pb.z); hh[7] = f2b(pb.w);
            *(bf16x8*)&xb[(t + 1) & 1][rr * HSTR + f0] = xv;
        }
        if (t > 0) {
            // ---- wait + tagged spin (first check usually fresh: load overlapped MFMA)
            wait_vm2(A1, A2);
            __builtin_amdgcn_sched_barrier(0);
            int guard = 0;
            while (A1.w != (u32)t) {
                if (++guard > SPIN_CAP) break;   // fast-fail, never timeout
                __builtin_amdgcn_s_sleep(1);
                A1 = ld_sc16(A1p);
            }
            guard = 0;
            while (A2.w != (u32)t) {
                if (++guard > SPIN_CAP) break;
                __builtin_amdgcn_s_sleep(1);
                A2 = ld_sc16(A2p);
            }
            *(u32*)&hsb[lo1] = A1.x; *(u32*)&hsb[lo1 + 2] = A1.y;
            *(u32*)&hsb[lo2] = A2.x; *(u32*)&hsb[lo2 + 2] = A2.y;
        }
        __syncthreads();   // (C) hsb + xb ready; drains only LDS writes (no fresh vmem!)
        // ---- issue x[t+2] prefetch AFTER the barrier: consumed at t+1's commit (~800 cy),
        //      fully drained only at t+1's spin wait (~1100 cy) -> HBM latency covered
        if (t + 2 < NL) {
            const float* px = &x[((size_t)(b0 + rr) * NL + (t + 2)) * ND + f0];
            pa = *(const float4*)px; pb = *(const float4*)(px + 4);
        }
        if (t > 0) {
            // ---- h-part MFMA into the same 4 chains
#pragma unroll
            for (int kk = 0; kk < 16; kk += 4) {
                const u16* hbp = &hsb[(lane & 3) * HSTR + quad * 8];
                ac0 = MF(*(bf16x8*)&hbp[(kk + 0) * 32], bwh[kk + 0], ac0);
                ac1 = MF(*(bf16x8*)&hbp[(kk + 1) * 32], bwh[kk + 1], ac1);
                ac2 = MF(*(bf16x8*)&hbp[(kk + 2) * 32], bwh[kk + 2], ac2);
                ac3 = MF(*(bf16x8*)&hbp[(kk + 3) * 32], bwh[kk + 3], ac3);
            }
        }
        f32x4 acc = (ac0 + ac1) + (ac2 + ac3);
        {   // ---- wave-local cell: gather the 4 gates of (row gidx, col cidx) via shfl_xor.
            float a0 = acc[0], a1 = acc[1], a2 = acc[2], a3 = acc[3];
            auto ext = [&](int i) {
                float t01 = (i & 1) ? a1 : a0;
                float t23 = (i & 1) ? a3 : a2;
                return (i & 2) ? t23 : t01;
            };
            float own = ext(gidx);
            float r1v = __shfl_xor(ext(gidx ^ 1), 1);
            float r2v = __shfl_xor(ext(gidx ^ 2), 2);
            float r3v = __shfl_xor(ext(gidx ^ 3), 3);
            auto pick = [&](int i) {
                float t01 = (i & 1) ? r1v : own;
                float t23 = (i & 1) ? r3v : r2v;
                return (i & 2) ? t23 : t01;
            };
            float gi = pick(gidx) + cbv0;        // gate 0 (i)
            float gf = pick(gidx ^ 1) + cbv1;    // gate 1 (f)
            float gg = pick(gidx ^ 2) + cbv2;    // gate 2 (g)
            float go = pick(gidx ^ 3) + cbv3;    // gate 3 (o)
            float iv = sigm_f(gi), fv = sigm_f(gf), ov = sigm_f(go);
            float gv = tanh_f(gg);
            c_reg = fv * c_reg + iv * gv;
            unsigned h32 = (unsigned)f2b(ov * tanh_f(c_reg));
            // publish: builder lane r (<4) gathers its row's 4 cols from lanes r,4+r,8+r,12+r
            unsigned s1 = __shfl(h32, (l & 3) + 4);
            unsigned s2 = __shfl(h32, (l & 3) + 8);
            unsigned s3 = __shfl(h32, (l & 3) + 12);
            if (l < 4) {
                u32x4 U;
                U.x = h32 | (s1 << 16);
                U.y = s2 | (s3 << 16);
                U.z = 0u;
                U.w = (u32)(t + 1);
                st_sc16(myst + (t & 1) * 512 + l * 4, U);
                // lstm_out write off the sync path (row l, cols jj+w*4..+3)
                *(u64*)&out[((size_t)(b0 + l) * NL + t) * NH + jj + w * 4] =
                    (u64)U.x | ((u64)U.y << 32);
            }
        }
    }
}

// Fused: Q = x@Wm^T+bm (prologue), flash attention with decayed-causal scores,
// FF head relu(W@W1^T+b1)@W2^T+b2 (epilogue). 16-row q tiles, 512 threads.
// (v7-validated: bf16 pre-cast weights, single-cvt prologue, wave-parallel softmax.)
__global__ __launch_bounds__(512) void k_attn(const float* __restrict__ x,
                                              const u16* __restrict__ Wmb,
                                              const float* __restrict__ bm,
                                              const u16* __restrict__ kv,
                                              const u16* __restrict__ W1b,
                                              const float* __restrict__ b1,
                                              const u16* __restrict__ W2b,
                                              const float* __restrict__ b2,
                                              float* __restrict__ outp) {
    __shared__ __align__(16) u16 Qs[16 * 520];
    __shared__ __align__(16) u16 Vt[512 * 40];
    __shared__ float Sbuf[16 * 33];
    __shared__ __align__(16) u16 Pbuf[16 * 40];
    __shared__ float alpha_s[16];
    __shared__ float l_s[16];
    int b = blockIdx.x, qt = blockIdx.y;
    int tid = threadIdx.x, w = tid >> 6, l = tid & 63, quad = l >> 4, lane = l & 15;

    {   // prologue: Qs[16][512] = x_tile @ Wm^T + bm
        const float* xq = x + ((size_t)b * NL + qt * 16 + lane) * ND;
        f32x4 aq0 = {}, aq1 = {}, aq2 = {}, aq3 = {};
#pragma unroll 4
        for (int kk = 0; kk < 16; kk++) {
            bf16x8 a = cvt8(&xq[kk * 32 + quad * 8]);
            int koff = kk * 32 + quad * 8;
            aq0 = MF(a, *(const bf16x8*)&Wmb[(size_t)((w * 4 + 0) * 16 + lane) * ND + koff], aq0);
            aq1 = MF(a, *(const bf16x8*)&Wmb[(size_t)((w * 4 + 1) * 16 + lane) * ND + koff], aq1);
            aq2 = MF(a, *(const bf16x8*)&Wmb[(size_t)((w * 4 + 2) * 16 + lane) * ND + koff], aq2);
            aq3 = MF(a, *(const bf16x8*)&Wmb[(size_t)((w * 4 + 3) * 16 + lane) * ND + koff], aq3);
        }
        f32x4 aqs[4] = {aq0, aq1, aq2, aq3};
#pragma unroll
        for (int nt2 = 0; nt2 < 4; nt2++) {
            int n = (w * 4 + nt2) * 16 + lane;
            float bmv = bm[n];
#pragma unroll
            for (int r = 0; r < 4; r++)
                Qs[(quad * 4 + r) * 520 + n] = f2b(aqs[nt2][r] + bmv);
        }
    }
    float m_run = -30000.f, l_run = 0.f;
    f32x4 acc[4] = {};
    __syncthreads();

    int st_max = ((qt << 4) + 15) >> 5;
    for (int st = 0; st <= st_max; st++) {
        if (w < 2) {  // QK^T: S[16][32], waves 0..1
            int ni = w;
            f32x4 s = {};
            const u16* krow = kv + ((size_t)b * NL + st * 32 + ni * 16 + lane) * NH;
#pragma unroll 4
            for (int kk = 0; kk < 16; kk++)
                s = MF(*(bf16x8*)&Qs[lane * 520 + kk * 32 + quad * 8],
                       *(const bf16x8*)&krow[kk * 32 + quad * 8], s);
            int scol = st * 32 + ni * 16 + lane;
#pragma unroll
            for (int r = 0; r < 4; r++) {
                int trow = (qt << 4) + quad * 4 + r;
                int dt = trow - scol;
                float v = (dt < 0) ? -30000.f : s[r] * __expf(-0.6f * (float)dt);
                Sbuf[(quad * 4 + r) * 33 + ni * 16 + lane] = v;
            }
        } else if (w >= 4) {  // stage V^T[512][32]
            int t2 = tid & 255;
            int srow = t2 >> 3, dseg = t2 & 7;
            const u16* vsrc = kv + ((size_t)b * NL + st * 32 + srow) * NH + dseg * 64;
#pragma unroll
            for (int i = 0; i < 8; i++) {
                union { uint4 v; u16 h[8]; } u;
                u.v = *(const uint4*)&vsrc[i * 8];
                int d0 = dseg * 64 + i * 8;
#pragma unroll
                for (int j2 = 0; j2 < 8; j2++) Vt[(d0 + j2) * 40 + srow] = u.h[j2];
            }
        }
        __syncthreads();
        if (tid < 64) {  // wave-parallel online softmax: 4 lanes/row, 8 cols each
            int m = tid >> 2, c0 = (tid & 3) * 8;
            float vmax = -30000.f;
#pragma unroll
            for (int i = 0; i < 8; i++) vmax = fmaxf(vmax, Sbuf[m * 33 + c0 + i]);
            vmax = fmaxf(vmax, __shfl_xor(vmax, 1));
            vmax = fmaxf(vmax, __shfl_xor(vmax, 2));
            float mnew = fmaxf(m_run, vmax);
            float al = __expf(m_run - mnew);
            float lsum = 0.f;
#pragma unroll
            for (int i = 0; i < 8; i++) {
                float p = __expf(Sbuf[m * 33 + c0 + i] - mnew);
                lsum += p;
                Pbuf[m * 40 + c0 + i] = f2b(p);
            }
            lsum += __shfl_xor(lsum, 1);
            lsum += __shfl_xor(lsum, 2);
            l_run = l_run * al + lsum;
            m_run = mnew;
            if ((tid & 3) == 0) { alpha_s[m] = al; l_s[m] = l_run; }
        }
        __syncthreads();
        {   // PV
            float a0 = alpha_s[quad * 4 + 0];
            float a1 = alpha_s[quad * 4 + 1];
            float a2 = alpha_s[quad * 4 + 2];
            float a3 = alpha_s[quad * 4 + 3];
            bf16x8 afrag = *(bf16x8*)&Pbuf[lane * 40 + quad * 8];
#pragma unroll
            for (int di = 0; di < 4; di++) {
                int dtile = w * 4 + di;
                f32x4 c = acc[di];
                c[0] *= a0; c[1] *= a1; c[2] *= a2; c[3] *= a3;
                acc[di] = MF(afrag, *(bf16x8*)&Vt[(dtile * 16 + lane) * 40 + quad * 8], c);
            }
        }
        __syncthreads();
    }

    u16* Wt = Vt;   // weighted -> LDS
    {
        float li0 = 1.f / l_s[quad * 4 + 0];
        float li1 = 1.f / l_s[quad * 4 + 1];
        float li2 = 1.f / l_s[quad * 4 + 2];
        float li3 = 1.f / l_s[quad * 4 + 3];
#pragma unroll
        for (int di = 0; di < 4; di++) {
            int col = (w * 4 + di) * 16 + lane;
            Wt[(quad * 4 + 0) * 520 + col] = f2b(acc[di][0] * li0);
            Wt[(quad * 4 + 1) * 520 + col] = f2b(acc[di][1] * li1);
            Wt[(quad * 4 + 2) * 520 + col] = f2b(acc[di][2] * li2);
            Wt[(quad * 4 + 3) * 520 + col] = f2b(acc[di][3] * li3);
        }
    }
    __syncthreads();
    u16* H1 = Qs;
    {   // H1[16][256] = relu(Wt @ W1^T + b1)
#pragma unroll
        for (int nt2 = 0; nt2 < 2; nt2++) {
            int n = (w * 2 + nt2) * 16 + lane;
            const u16* w1p = W1b + (size_t)n * ND;
            f32x4 a1 = {};
#pragma unroll 4
            for (int kk = 0; kk < 16; kk++)
                a1 = MF(*(bf16x8*)&Wt[lane * 520 + kk * 32 + quad * 8],
                        *(const bf16x8*)&w1p[kk * 32 + quad * 8], a1);
            float b1v = b1[n];
#pragma unroll
            for (int r = 0; r < 4; r++)
                H1[(quad * 4 + r) * 264 + n] = f2b(fmaxf(a1[r] + b1v, 0.f));
        }
    }
    __syncthreads();
    if (w < 7) {  // out[16][100] = H1 @ W2^T + b2
        int n = w * 16 + lane;
        int nc = n < NOUT ? n : NOUT - 1;
        const u16* w2p = W2b + (size_t)nc * NFF;
        f32x4 a2 = {};
#pragma unroll
        for (int kk = 0; kk < 8; kk++)
            a2 = MF(*(bf16x8*)&H1[lane * 264 + kk * 32 + quad * 8],
                    *(const bf16x8*)&w2p[kk * 32 + quad * 8], a2);
        if (n < NOUT) {
            float b2v = b2[n];
#pragma unroll
            for (int r = 0; r < 4; r++)
                outp[((size_t)b * NL + (qt << 4) + quad * 4 + r) * NOUT + n] = a2[r] + b2v;
        }
    }
}

extern "C" void kernel_launch(void* const* d_in, const int* in_sizes, int n_in,
                              void* d_out, int out_size, void* d_ws, size_t ws_size,
                              hipStream_t stream) {
    const float* x        = (const float*)d_in[0];
    const int*   concepts = (const int*)d_in[1];
    const float* emb      = (const float*)d_in[2];
    const float* Wih      = (const float*)d_in[3];
    const float* Whh      = (const float*)d_in[4];
    const float* bih      = (const float*)d_in[5];
    const float* bhh      = (const float*)d_in[6];
    const float* Wm       = (const float*)d_in[7];
    const float* bm       = (const float*)d_in[8];
    const float* W1       = (const float*)d_in[9];
    const float* b1       = (const float*)d_in[10];
    const float* W2       = (const float*)d_in[11];
    const float* b2       = (const float*)d_in[12];
    float* outp = (float*)d_out;

    char* ws = (char*)d_ws;
    size_t off = 0;
    u16* lstm_out = (u16*)(ws + off); off += (size_t)NB * NL * NH * 2;   // 32 MB
    float* cbias  = (float*)(ws + off); off += (size_t)NB * G4 * 4;      // 256 KB
    u32x4* hx     = (u32x4*)(ws + off); off += (size_t)8 * 1024 * 16;    // 128 KB tagged h units
    u16* Wmb      = (u16*)(ws + off); off += (size_t)ND * ND * 2;        // 512 KB
    u16* W1b      = (u16*)(ws + off); off += (size_t)NFF * ND * 2;       // 256 KB
    u16* W2b      = (u16*)(ws + off); off += (size_t)NOUT * NFF * 2;     // 50 KB

    (void)hipMemsetAsync(hx, 0, (size_t)8 * 1024 * 16, stream);  // tags=0 != any expected tag
    k_wcast<<<(ND * ND / 4 + 255) / 256, 256, 0, stream>>>(Wm, Wmb, ND * ND / 4);
    k_wcast<<<(NFF * ND / 4 + 255) / 256, 256, 0, stream>>>(W1, W1b, NFF * ND / 4);
    k_wcast<<<(NOUT * NFF / 4 + 255) / 256, 256, 0, stream>>>(W2, W2b, NOUT * NFF / 4);
    k_cbias<<<dim3(NB, G4 / 256), 256, 0, stream>>>(emb, concepts, Wih, bih, bhh, cbias);
    k_lstm<<<256, 256, 0, stream>>>(x, Wih, Whh, cbias, lstm_out, hx);
    k_attn<<<dim3(NB, NL / 16), 512, 0, stream>>>(x, Wmb, bm, lstm_out, W1b, b1, W2b, b2, outp);
}

// Round 10
// 2124.621 us; speedup vs baseline: 1.4674x; 1.4674x over previous
//
#include <hip/hip_runtime.h>
#include <hip/hip_bf16.h>
#include <stdint.h>

typedef unsigned short u16;
typedef unsigned int u32;
typedef unsigned long long u64;
typedef float f32x4 __attribute__((ext_vector_type(4)));
typedef short bf16x8 __attribute__((ext_vector_type(8)));
typedef unsigned u32x4 __attribute__((ext_vector_type(4)));   // native vector for asm 'v'

#define NB 32
#define NL 1024
#define ND 512
#define NH 512
#define G4 2048
#define NOUT 100
#define NFF 256
#define HSTR 528   // LDS row stride (halfwords): 264 dwords == 8 mod 32 -> uniform 2-way (free) a-frag reads
#define SPIN_CAP (1 << 15)   // fast-fail bound: any exchange pathology fails the bench, never hangs

__device__ inline u16 f2b(float f) {
    union { float f; unsigned i; } c; c.f = f;
    unsigned i = c.i;
    return (u16)((i + 0x7FFFu + ((i >> 16) & 1u)) >> 16);
}
__device__ inline bf16x8 cvt8(const float* __restrict__ p) {
    float4 a = *(const float4*)p;
    float4 b = *(const float4*)(p + 4);
    bf16x8 r;
    u16* h = (u16*)&r;
    h[0] = f2b(a.x); h[1] = f2b(a.y); h[2] = f2b(a.z); h[3] = f2b(a.w);
    h[4] = f2b(b.x); h[5] = f2b(b.y); h[6] = f2b(b.z); h[7] = f2b(b.w);
    return r;
}
__device__ inline f32x4 MF(bf16x8 a, bf16x8 b, f32x4 c) {
    return __builtin_amdgcn_mfma_f32_16x16x32_bf16(a, b, c, 0, 0, 0);
}
__device__ inline float tanh_f(float x) {
    float xx = fminf(fmaxf(x, -15.f), 15.f);
    float e = __expf(2.f * xx);
    return (e - 1.f) / (e + 1.f);
}
__device__ inline float sigm_f(float x) { return 1.f / (1.f + __expf(-x)); }

// 16-B SYSTEM-coherent load/store (sc0 sc1: scope >= agent, to the coherence point).
// One dwordx4 = one LLC request -> tag+payload move atomically within the aligned 16 B.
__device__ inline void ld2_issue(const u32x4* p1, const u32x4* p2, u32x4& r1, u32x4& r2) {
    asm volatile("global_load_dwordx4 %0, %2, off sc0 sc1\n\t"
                 "global_load_dwordx4 %1, %3, off sc0 sc1"
                 : "=&v"(r1), "=&v"(r2) : "v"(p1), "v"(p2) : "memory");
}
__device__ inline void ld2_sc16(const u32x4* p1, const u32x4* p2, u32x4& r1, u32x4& r2) {
    asm volatile("global_load_dwordx4 %0, %2, off sc0 sc1\n\t"
                 "global_load_dwordx4 %1, %3, off sc0 sc1\n\t"
                 "s_waitcnt vmcnt(0)"
                 : "=&v"(r1), "=&v"(r2) : "v"(p1), "v"(p2) : "memory");
}
__device__ inline void wait_vm2(u32x4& r1, u32x4& r2) {
    asm volatile("s_waitcnt vmcnt(0)" : "+v"(r1), "+v"(r2) :: "memory");
}
__device__ inline void st_sc16(u32x4* p, u32x4 v) {
    asm volatile("global_store_dwordx4 %0, %1, off sc0 sc1"
                 :: "v"(p), "v"(v) : "memory");
}

// f32 -> bf16 pre-cast (weights for k_attn): one quad per thread.
__global__ __launch_bounds__(256) void k_wcast(const float* __restrict__ s,
                                               u16* __restrict__ d, int n4) {
    int i = blockIdx.x * 256 + threadIdx.x;
    if (i >= n4) return;
    float4 v = *(const float4*)&s[(size_t)i * 4];
    u64 pk = (u64)f2b(v.x) | ((u64)f2b(v.y) << 16) |
             ((u64)f2b(v.z) << 32) | ((u64)f2b(v.w) << 48);
    *(u64*)&d[(size_t)i * 4] = pk;
}

// cbias[b][r] = emb[concepts[b]] . Wih[r, 512:1024] + bih[r] + bhh[r]   (all fp32)
__global__ __launch_bounds__(256) void k_cbias(const float* __restrict__ emb,
                                               const int* __restrict__ concepts,
                                               const float* __restrict__ Wih,
                                               const float* __restrict__ bih,
                                               const float* __restrict__ bhh,
                                               float* __restrict__ cbias) {
    __shared__ float e[ND];
    int b = blockIdx.x;
    int r = blockIdx.y * 256 + threadIdx.x;
    int c = concepts[b];
    for (int i = threadIdx.x; i < ND; i += 256) e[i] = emb[c * ND + i];
    __syncthreads();
    const float* wrow = Wih + (size_t)r * 1024 + 512;
    float acc = 0.f;
#pragma unroll 4
    for (int k4 = 0; k4 < 128; k4++) {
        float4 wv = *(const float4*)&wrow[k4 * 4];
        acc += e[k4 * 4 + 0] * wv.x + e[k4 * 4 + 1] * wv.y +
               e[k4 * 4 + 2] * wv.z + e[k4 * 4 + 3] * wv.w;
    }
    cbias[b * G4 + r] = acc + bih[r] + bhh[r];
}

// Persistent LSTM, batch-split: 8 groups x 32 blocks; group g owns batch rows [4g,4g+4),
// block k owns h lanes [16k,16k+16).
// v11 = EXACT v8 loop order (measured 1550 us) + SPIN_CAP + merged spin retry.
//  v9/v10 lesson (measured: 1550 -> 2490 us, FETCH +57 MB): spin loads issued at the
//  TOP of the iteration sample the tags before producers publish -> always-stale first
//  sample -> retry storm (system-scope retries refetch from fabric). The sampling point
//  must match data arrival: v8's position (after x-commit, before x-MFMA) is the proven
//  sweet spot. Reverted; do not re-order this loop without phase instrumentation.
//  - Loop: commit x[t+1] -> spin-issue -> x-MFMA -> spin-wait+hsb -> prefetch-issue ->
//    barrier C -> h-MFMA -> wave-local cell -> publish.
//  - Merged retry loop: one ld2+vmcnt(0) reloads BOTH units (was 2 serial loops), no
//    sleep on first retry -> halves worst-case retry latency at the same sampling point.
//  - All v8-validated structure: wave-local cell via gate-interleaved B cols, tagged
//    16-B exchange units, weights in regs, HSTR=528.
__global__ __launch_bounds__(256, 1) void k_lstm(const float* __restrict__ x,
                                                 const float* __restrict__ Wih,
                                                 const float* __restrict__ Whh,
                                                 const float* __restrict__ cbias,
                                                 u16* __restrict__ out,
                                                 u32x4* __restrict__ hx) {
    __shared__ __align__(16) u16 hsb[4 * HSTR];         // h[t-1] tile, bf16
    __shared__ __align__(16) u16 xb[2][4 * HSTR];       // x double buffer, bf16
    int g = blockIdx.x & 7, k = blockIdx.x >> 3;
    int tid = threadIdx.x;
    int w = tid >> 6, l = tid & 63, quad = l >> 4, lane = l & 15;
    int jj = k * 16;
    int b0 = g * 4;
    int rr = w, f0 = l * 8;
    int gidx = l & 3;          // gate index of this lane's C column
    int cidx = lane >> 2;      // h-col offset (0..3) within the wave's 4 columns

    // ---- init: weights -> registers (gate-interleaved B cols), cbias regs, x[0] -> LDS
    bf16x8 bwx[16], bwh[16];
    float cbv0, cbv1, cbv2, cbv3;
    {
        int n = lane;                       // B col
        int wrow = (n & 3) * 512 + jj + w * 4 + (n >> 2);   // weight row for col n
        int q4 = l >> 4;
        const float* wsrc = Wih + (size_t)wrow * 1024 + q4 * 8;  // x-part
        const float* hsrc = Whh + (size_t)wrow * 512 + q4 * 8;
#pragma unroll
        for (int kk = 0; kk < 16; kk++) {
            bwx[kk] = cvt8(wsrc + kk * 32);
            bwh[kk] = cvt8(hsrc + kk * 32);
        }
        // cell constants for (row=gidx, col=jj+w*4+cidx), one per gate
        size_t cb = (size_t)(b0 + gidx) * G4 + jj + w * 4 + cidx;
        cbv0 = cbias[cb + 0 * 512];
        cbv1 = cbias[cb + 1 * 512];
        cbv2 = cbias[cb + 2 * 512];
        cbv3 = cbias[cb + 3 * 512];
        *(bf16x8*)&xb[0][rr * HSTR + f0] = cvt8(&x[((size_t)(b0 + rr) * NL) * ND + f0]);
    }

    // ---- consumer precompute: 512 units (32 blocks x 4 rows x 4 waves), exactly 2/thread
    // unit u = p*16 + r*4 + wv: payload = h[row r][p*16 + wv*4 .. +3]
    u32x4* hxg = hx + (size_t)g * 1024;              // per-group: 2 parity x 512 units
    int p1 = tid >> 4, r1 = (tid >> 2) & 3, w1 = tid & 3;
    int lo1 = r1 * HSTR + p1 * 16 + w1 * 4;          // hsb halfword offset (unit 1)
    int lo2 = lo1 + 256;                             // unit 2: p += 16
    const u32x4* a1base = hxg + tid;
    const u32x4* a2base = hxg + 256 + tid;
    u32x4* myst = hxg + k * 16 + w;                  // + r*4 chosen by builder lane

    // preload x[1] into prefetch regs (committed at top of iter 0)
    float4 pa, pb;
    {
        const float* px = &x[((size_t)(b0 + rr) * NL + 1) * ND + f0];
        pa = *(const float4*)px; pb = *(const float4*)(px + 4);
    }
    __syncthreads();

    float c_reg = 0.f;   // cell state for (row gidx, col jj+w*4+cidx); dup across quads

    for (int t = 0; t < NL; t++) {
        // ---- commit x[t+1] (loads issued one full iteration ago -> no stall)
        if (t + 1 < NL) {
            bf16x8 xv; u16* hh = (u16*)&xv;
            hh[0] = f2b(pa.x); hh[1] = f2b(pa.y); hh[2] = f2b(pa.z); hh[3] = f2b(pa.w);
            hh[4] = f2b(pb.x); hh[5] = f2b(pb.y); hh[6] = f2b(pb.z); hh[7] = f2b(pb.w);
            *(bf16x8*)&xb[(t + 1) & 1][rr * HSTR + f0] = xv;
        }
        // ---- issue spin loads (v8's proven sampling point: after commit, before x-MFMA)
        u32x4 A1 = {}, A2 = {};
        const u32x4* A1p = a1base;
        const u32x4* A2p = a2base;
        if (t > 0) {
            int poff = ((t - 1) & 1) * 512;
            A1p = a1base + poff;
            A2p = a2base + poff;
            ld2_issue(A1p, A2p, A1, A2);
        }
        // ---- x-part MFMA, 4 independent accumulator chains (LDS/lgkm only)
        f32x4 ac0 = {}, ac1 = {}, ac2 = {}, ac3 = {};
#pragma unroll
        for (int kk = 0; kk < 16; kk += 4) {
            const u16* xbp = &xb[t & 1][(lane & 3) * HSTR + quad * 8];
            ac0 = MF(*(bf16x8*)&xbp[(kk + 0) * 32], bwx[kk + 0], ac0);
            ac1 = MF(*(bf16x8*)&xbp[(kk + 1) * 32], bwx[kk + 1], ac1);
            ac2 = MF(*(bf16x8*)&xbp[(kk + 2) * 32], bwx[kk + 2], ac2);
            ac3 = MF(*(bf16x8*)&xbp[(kk + 3) * 32], bwx[kk + 3], ac3);
        }
        if (t > 0) {
            // ---- wait + merged tagged spin (one ld2+vmcnt reloads both; no first sleep)
            wait_vm2(A1, A2);
            __builtin_amdgcn_sched_barrier(0);
            int guard = 0;
            while (A1.w != (u32)t || A2.w != (u32)t) {
                if (++guard > SPIN_CAP) break;   // fast-fail, never timeout
                if (guard > 1) __builtin_amdgcn_s_sleep(1);
                ld2_sc16(A1p, A2p, A1, A2);
                __builtin_amdgcn_sched_barrier(0);
            }
            *(u32*)&hsb[lo1] = A1.x; *(u32*)&hsb[lo1 + 2] = A1.y;
            *(u32*)&hsb[lo2] = A2.x; *(u32*)&hsb[lo2 + 2] = A2.y;
        }
        // ---- issue x[t+2] prefetch (pre-barrier, as in v8 — do not move, see header)
        if (t + 2 < NL) {
            const float* px = &x[((size_t)(b0 + rr) * NL + (t + 2)) * ND + f0];
            pa = *(const float4*)px; pb = *(const float4*)(px + 4);
        }
        __syncthreads();   // (C) hsb + xb ready for all waves
        if (t > 0) {
            // ---- h-part MFMA into the same 4 chains
#pragma unroll
            for (int kk = 0; kk < 16; kk += 4) {
                const u16* hbp = &hsb[(lane & 3) * HSTR + quad * 8];
                ac0 = MF(*(bf16x8*)&hbp[(kk + 0) * 32], bwh[kk + 0], ac0);
                ac1 = MF(*(bf16x8*)&hbp[(kk + 1) * 32], bwh[kk + 1], ac1);
                ac2 = MF(*(bf16x8*)&hbp[(kk + 2) * 32], bwh[kk + 2], ac2);
                ac3 = MF(*(bf16x8*)&hbp[(kk + 3) * 32], bwh[kk + 3], ac3);
            }
        }
        f32x4 acc = (ac0 + ac1) + (ac2 + ac3);
        {   // ---- wave-local cell: gather the 4 gates of (row gidx, col cidx) via shfl_xor.
            float a0 = acc[0], a1 = acc[1], a2 = acc[2], a3 = acc[3];
            auto ext = [&](int i) {
                float t01 = (i & 1) ? a1 : a0;
                float t23 = (i & 1) ? a3 : a2;
                return (i & 2) ? t23 : t01;
            };
            float own = ext(gidx);
            float r1v = __shfl_xor(ext(gidx ^ 1), 1);
            float r2v = __shfl_xor(ext(gidx ^ 2), 2);
            float r3v = __shfl_xor(ext(gidx ^ 3), 3);
            auto pick = [&](int i) {
                float t01 = (i & 1) ? r1v : own;
                float t23 = (i & 1) ? r3v : r2v;
                return (i & 2) ? t23 : t01;
            };
            float gi = pick(gidx) + cbv0;        // gate 0 (i)
            float gf = pick(gidx ^ 1) + cbv1;    // gate 1 (f)
            float gg = pick(gidx ^ 2) + cbv2;    // gate 2 (g)
            float go = pick(gidx ^ 3) + cbv3;    // gate 3 (o)
            float iv = sigm_f(gi), fv = sigm_f(gf), ov = sigm_f(go);
            float gv = tanh_f(gg);
            c_reg = fv * c_reg + iv * gv;
            unsigned h32 = (unsigned)f2b(ov * tanh_f(c_reg));
            // publish: builder lane r (<4) gathers its row's 4 cols from lanes r,4+r,8+r,12+r
            unsigned s1 = __shfl(h32, (l & 3) + 4);
            unsigned s2 = __shfl(h32, (l & 3) + 8);
            unsigned s3 = __shfl(h32, (l & 3) + 12);
            if (l < 4) {
                u32x4 U;
                U.x = h32 | (s1 << 16);
                U.y = s2 | (s3 << 16);
                U.z = 0u;
                U.w = (u32)(t + 1);
                st_sc16(myst + (t & 1) * 512 + l * 4, U);
                // lstm_out write off the sync path (row l, cols jj+w*4..+3)
                *(u64*)&out[((size_t)(b0 + l) * NL + t) * NH + jj + w * 4] =
                    (u64)U.x | ((u64)U.y << 32);
            }
        }
    }
}

// Fused: Q = x@Wm^T+bm (prologue), flash attention with decayed-causal scores,
// FF head relu(W@W1^T+b1)@W2^T+b2 (epilogue). 16-row q tiles, 512 threads.
// (v7-validated: bf16 pre-cast weights, single-cvt prologue, wave-parallel softmax.)
__global__ __launch_bounds__(512) void k_attn(const float* __restrict__ x,
                                              const u16* __restrict__ Wmb,
                                              const float* __restrict__ bm,
                                              const u16* __restrict__ kv,
                                              const u16* __restrict__ W1b,
                                              const float* __restrict__ b1,
                                              const u16* __restrict__ W2b,
                                              const float* __restrict__ b2,
                                              float* __restrict__ outp) {
    __shared__ __align__(16) u16 Qs[16 * 520];
    __shared__ __align__(16) u16 Vt[512 * 40];
    __shared__ float Sbuf[16 * 33];
    __shared__ __align__(16) u16 Pbuf[16 * 40];
    __shared__ float alpha_s[16];
    __shared__ float l_s[16];
    int b = blockIdx.x, qt = blockIdx.y;
    int tid = threadIdx.x, w = tid >> 6, l = tid & 63, quad = l >> 4, lane = l & 15;

    {   // prologue: Qs[16][512] = x_tile @ Wm^T + bm
        const float* xq = x + ((size_t)b * NL + qt * 16 + lane) * ND;
        f32x4 aq0 = {}, aq1 = {}, aq2 = {}, aq3 = {};
#pragma unroll 4
        for (int kk = 0; kk < 16; kk++) {
            bf16x8 a = cvt8(&xq[kk * 32 + quad * 8]);
            int koff = kk * 32 + quad * 8;
            aq0 = MF(a, *(const bf16x8*)&Wmb[(size_t)((w * 4 + 0) * 16 + lane) * ND + koff], aq0);
            aq1 = MF(a, *(const bf16x8*)&Wmb[(size_t)((w * 4 + 1) * 16 + lane) * ND + koff], aq1);
            aq2 = MF(a, *(const bf16x8*)&Wmb[(size_t)((w * 4 + 2) * 16 + lane) * ND + koff], aq2);
            aq3 = MF(a, *(const bf16x8*)&Wmb[(size_t)((w * 4 + 3) * 16 + lane) * ND + koff], aq3);
        }
        f32x4 aqs[4] = {aq0, aq1, aq2, aq3};
#pragma unroll
        for (int nt2 = 0; nt2 < 4; nt2++) {
            int n = (w * 4 + nt2) * 16 + lane;
            float bmv = bm[n];
#pragma unroll
            for (int r = 0; r < 4; r++)
                Qs[(quad * 4 + r) * 520 + n] = f2b(aqs[nt2][r] + bmv);
        }
    }
    float m_run = -30000.f, l_run = 0.f;
    f32x4 acc[4] = {};
    __syncthreads();

    int st_max = ((qt << 4) + 15) >> 5;
    for (int st = 0; st <= st_max; st++) {
        if (w < 2) {  // QK^T: S[16][32], waves 0..1
            int ni = w;
            f32x4 s = {};
            const u16* krow = kv + ((size_t)b * NL + st * 32 + ni * 16 + lane) * NH;
#pragma unroll 4
            for (int kk = 0; kk < 16; kk++)
                s = MF(*(bf16x8*)&Qs[lane * 520 + kk * 32 + quad * 8],
                       *(const bf16x8*)&krow[kk * 32 + quad * 8], s);
            int scol = st * 32 + ni * 16 + lane;
#pragma unroll
            for (int r = 0; r < 4; r++) {
                int trow = (qt << 4) + quad * 4 + r;
                int dt = trow - scol;
                float v = (dt < 0) ? -30000.f : s[r] * __expf(-0.6f * (float)dt);
                Sbuf[(quad * 4 + r) * 33 + ni * 16 + lane] = v;
            }
        } else if (w >= 4) {  // stage V^T[512][32]
            int t2 = tid & 255;
            int srow = t2 >> 3, dseg = t2 & 7;
            const u16* vsrc = kv + ((size_t)b * NL + st * 32 + srow) * NH + dseg * 64;
#pragma unroll
            for (int i = 0; i < 8; i++) {
                union { uint4 v; u16 h[8]; } u;
                u.v = *(const uint4*)&vsrc[i * 8];
                int d0 = dseg * 64 + i * 8;
#pragma unroll
                for (int j2 = 0; j2 < 8; j2++) Vt[(d0 + j2) * 40 + srow] = u.h[j2];
            }
        }
        __syncthreads();
        if (tid < 64) {  // wave-parallel online softmax: 4 lanes/row, 8 cols each
            int m = tid >> 2, c0 = (tid & 3) * 8;
            float vmax = -30000.f;
#pragma unroll
            for (int i = 0; i < 8; i++) vmax = fmaxf(vmax, Sbuf[m * 33 + c0 + i]);
            vmax = fmaxf(vmax, __shfl_xor(vmax, 1));
            vmax = fmaxf(vmax, __shfl_xor(vmax, 2));
            float mnew = fmaxf(m_run, vmax);
            float al = __expf(m_run - mnew);
            float lsum = 0.f;
#pragma unroll
            for (int i = 0; i < 8; i++) {
                float p = __expf(Sbuf[m * 33 + c0 + i] - mnew);
                lsum += p;
                Pbuf[m * 40 + c0 + i] = f2b(p);
            }
            lsum += __shfl_xor(lsum, 1);
            lsum += __shfl_xor(lsum, 2);
            l_run = l_run * al + lsum;
            m_run = mnew;
            if ((tid & 3) == 0) { alpha_s[m] = al; l_s[m] = l_run; }
        }
        __syncthreads();
        {   // PV
            float a0 = alpha_s[quad * 4 + 0];
            float a1 = alpha_s[quad * 4 + 1];
            float a2 = alpha_s[quad * 4 + 2];
            float a3 = alpha_s[quad * 4 + 3];
            bf16x8 afrag = *(bf16x8*)&Pbuf[lane * 40 + quad * 8];
#pragma unroll
            for (int di = 0; di < 4; di++) {
                int dtile = w * 4 + di;
                f32x4 c = acc[di];
                c[0] *= a0; c[1] *= a1; c[2] *= a2; c[3] *= a3;
                acc[di] = MF(afrag, *(bf16x8*)&Vt[(dtile * 16 + lane) * 40 + quad * 8], c);
            }
        }
        __syncthreads();
    }

    u16* Wt = Vt;   // weighted -> LDS
    {
        float li0 = 1.f / l_s[quad * 4 + 0];
        float li1 = 1.f / l_s[quad * 4 + 1];
        float li2 = 1.f / l_s[quad * 4 + 2];
        float li3 = 1.f / l_s[quad * 4 + 3];
#pragma unroll
        for (int di = 0; di < 4; di++) {
            int col = (w * 4 + di) * 16 + lane;
            Wt[(quad * 4 + 0) * 520 + col] = f2b(acc[di][0] * li0);
            Wt[(quad * 4 + 1) * 520 + col] = f2b(acc[di][1] * li1);
            Wt[(quad * 4 + 2) * 520 + col] = f2b(acc[di][2] * li2);
            Wt[(quad * 4 + 3) * 520 + col] = f2b(acc[di][3] * li3);
        }
    }
    __syncthreads();
    u16* H1 = Qs;
    {   // H1[16][256] = relu(Wt @ W1^T + b1)
#pragma unroll
        for (int nt2 = 0; nt2 < 2; nt2++) {
            int n = (w * 2 + nt2) * 16 + lane;
            const u16* w1p = W1b + (size_t)n * ND;
            f32x4 a1 = {};
#pragma unroll 4
            for (int kk = 0; kk < 16; kk++)
                a1 = MF(*(bf16x8*)&Wt[lane * 520 + kk * 32 + quad * 8],
                        *(const bf16x8*)&w1p[kk * 32 + quad * 8], a1);
            float b1v = b1[n];
#pragma unroll
            for (int r = 0; r < 4; r++)
                H1[(quad * 4 + r) * 264 + n] = f2b(fmaxf(a1[r] + b1v, 0.f));
        }
    }
    __syncthreads();
    if (w < 7) {  // out[16][100] = H1 @ W2^T + b2
        int n = w * 16 + lane;
        int nc = n < NOUT ? n : NOUT - 1;
        const u16* w2p = W2b + (size_t)nc * NFF;
        f32x4 a2 = {};
#pragma unroll
        for (int kk = 0; kk < 8; kk++)
            a2 = MF(*(bf16x8*)&H1[lane * 264 + kk * 32 + quad * 8],
                    *(const bf16x8*)&w2p[kk * 32 + quad * 8], a2);
        if (n < NOUT) {
            float b2v = b2[n];
#pragma unroll
            for (int r = 0; r < 4; r++)
                outp[((size_t)b * NL + (qt << 4) + quad * 4 + r) * NOUT + n] = a2[r] + b2v;
        }
    }
}

extern "C" void kernel_launch(void* const* d_in, const int* in_sizes, int n_in,
                              void* d_out, int out_size, void* d_ws, size_t ws_size,
                              hipStream_t stream) {
    const float* x        = (const float*)d_in[0];
    const int*   concepts = (const int*)d_in[1];
    const float* emb      = (const float*)d_in[2];
    const float* Wih      = (const float*)d_in[3];
    const float* Whh      = (const float*)d_in[4];
    const float* bih      = (const float*)d_in[5];
    const float* bhh      = (const float*)d_in[6];
    const float* Wm       = (const float*)d_in[7];
    const float* bm       = (const float*)d_in[8];
    const float* W1       = (const float*)d_in[9];
    const float* b1       = (const float*)d_in[10];
    const float* W2       = (const float*)d_in[11];
    const float* b2       = (const float*)d_in[12];
    float* outp = (float*)d_out;

    char* ws = (char*)d_ws;
    size_t off = 0;
    u16* lstm_out = (u16*)(ws + off); off += (size_t)NB * NL * NH * 2;   // 32 MB
    float* cbias  = (float*)(ws + off); off += (size_t)NB * G4 * 4;      // 256 KB
    u32x4* hx     = (u32x4*)(ws + off); off += (size_t)8 * 1024 * 16;    // 128 KB tagged h units
    u16* Wmb      = (u16*)(ws + off); off += (size_t)ND * ND * 2;        // 512 KB
    u16* W1b      = (u16*)(ws + off); off += (size_t)NFF * ND * 2;       // 256 KB
    u16* W2b      = (u16*)(ws + off); off += (size_t)NOUT * NFF * 2;     // 50 KB

    (void)hipMemsetAsync(hx, 0, (size_t)8 * 1024 * 16, stream);  // tags=0 != any expected tag
    k_wcast<<<(ND * ND / 4 + 255) / 256, 256, 0, stream>>>(Wm, Wmb, ND * ND / 4);
    k_wcast<<<(NFF * ND / 4 + 255) / 256, 256, 0, stream>>>(W1, W1b, NFF * ND / 4);
    k_wcast<<<(NOUT * NFF / 4 + 255) / 256, 256, 0, stream>>>(W2, W2b, NOUT * NFF / 4);
    k_cbias<<<dim3(NB, G4 / 256), 256, 0, stream>>>(emb, concepts, Wih, bih, bhh, cbias);
    k_lstm<<<256, 256, 0, stream>>>(x, Wih, Whh, cbias, lstm_out, hx);
    k_attn<<<dim3(NB, NL / 16), 512, 0, stream>>>(x, Wmb, bm, lstm_out, W1b, b1, W2b, b2, outp);
}